// Round 6
// baseline (252.121 us; speedup 1.0000x reference)
//
#include <hip/hip_runtime.h>
#include <math.h>

#define Dm   768
#define Hm   64
#define SEQ  4096
#define NB   4
#define NROW (NB * SEQ)

// scale 1/sqrt(64) and log2(e) folded into Wq at wconv time -> exp2 domain
#define QSCALE (0.125f * 1.4426950408889634f)

typedef _Float16 f16;
typedef __attribute__((ext_vector_type(8))) _Float16 f16x8;
typedef __attribute__((ext_vector_type(2))) __fp16 fp16x2_raw;
typedef __attribute__((ext_vector_type(4))) float f32x4;
typedef unsigned int uint;
typedef unsigned short ushort;

#define MFMAH(A, B, C) __builtin_amdgcn_mfma_f32_16x16x32_f16(A, B, C, 0, 0, 0)

__device__ __forceinline__ uint pkrtz(float a, float b) {
    fp16x2_raw r = __builtin_amdgcn_cvt_pkrtz(a, b);
    return __builtin_bit_cast(uint, r);
}
__device__ __forceinline__ ushort f2h(float f) {
    f16 h = (f16)f;
    return __builtin_bit_cast(ushort, h);
}
union F16x8U { uint u[4]; f16x8 v; };

// ---------------------------------------------------------------------------
// Kernel 0: W -> WTt f16, tiled [kt(24)][c(192)][kk(32)] so proj B-fragment
// loads are fully coalesced. c: 0-63 Q (QSCALE folded), 64-127 K, 128-191 V.
// ---------------------------------------------------------------------------
__global__ __launch_bounds__(256) void wconv(
    const float* __restrict__ Wq, const float* __restrict__ Wk,
    const float* __restrict__ Wv, ushort* __restrict__ WTt)
{
    const int c   = blockIdx.x;
    const int mat = c >> 6, col = c & 63;
    const float* W = (mat == 0) ? Wq : (mat == 1 ? Wk : Wv);
    const float sc = (mat == 0) ? QSCALE : 1.0f;
    for (int k = threadIdx.x; k < Dm; k += 256)
        WTt[((size_t)(k >> 5) * 192 + c) * 32 + (k & 31)] = f2h(W[k * 64 + col] * sc);
}

// ---------------------------------------------------------------------------
// Kernel 1: f16 MFMA QKV projection, LDS-free main loop, split-K=2.
// grid 512 x 256 (2 blocks/CU, 2 waves/SIMD). Block = 32 rows.
// Wave (rt = w&1, kh = w>>1): rows gr0+rt*16.., k in [kh*384, +384) = 12 iters.
// A: ix fp32 -> registers (2 dwordx4 gathers/iter) -> pkrtz.
// B: WTt coalesced dwordx4 frags, register-dbuf. 12 MFMA/iter.
// Split-K combine through LDS; epilogue writes Q row-major, K/V frag-tiled:
//   Kt[n>>4][d>>5][(d>>3)&3][n&15][d&7], Vt[n>>5][d>>4][(n>>3)&3][d&15][n&7].
// ---------------------------------------------------------------------------
__global__ __launch_bounds__(256) void proj(
    const float* __restrict__ ix, const ushort* __restrict__ WTt,
    ushort* __restrict__ Qw, ushort* __restrict__ Kt, ushort* __restrict__ Vt)
{
    __shared__ __align__(16) float comb[2][3072];   // 24 KiB

    const int t    = threadIdx.x;
    const int lane = t & 63;
    const int w    = __builtin_amdgcn_readfirstlane(t >> 6);
    const int rt   = w & 1, kh = w >> 1;
    const int q15  = lane & 15, quad = lane >> 4;
    const int gr0  = blockIdx.x * 32;
    const int row  = gr0 + rt * 16 + q15;

    const float*  Ab = ix + (size_t)row * Dm + kh * 384 + quad * 8;
    const ushort* Bb = WTt + ((size_t)(kh * 12) * 192 + q15) * 32 + quad * 8;

    f32x4 acc[12];
#pragma unroll
    for (int ct = 0; ct < 12; ++ct) acc[ct] = (f32x4){0.f, 0.f, 0.f, 0.f};

    f32x4 Af[2][2];
    f16x8 Bf[2][12];
    Af[0][0] = *(const f32x4*)(Ab);
    Af[0][1] = *(const f32x4*)(Ab + 4);
#pragma unroll
    for (int ct = 0; ct < 12; ++ct)
        Bf[0][ct] = *(const f16x8*)(Bb + ct * 512);

#pragma unroll 2
    for (int it = 0; it < 12; ++it) {
        const int cur = it & 1, nxt = cur ^ 1;
        if (it < 11) {
            Af[nxt][0] = *(const f32x4*)(Ab + (it + 1) * 32);
            Af[nxt][1] = *(const f32x4*)(Ab + (it + 1) * 32 + 4);
#pragma unroll
            for (int ct = 0; ct < 12; ++ct)
                Bf[nxt][ct] = *(const f16x8*)(Bb + (size_t)(it + 1) * 6144 + ct * 512);
        }
        F16x8U af;
        af.u[0] = pkrtz(Af[cur][0].x, Af[cur][0].y);
        af.u[1] = pkrtz(Af[cur][0].z, Af[cur][0].w);
        af.u[2] = pkrtz(Af[cur][1].x, Af[cur][1].y);
        af.u[3] = pkrtz(Af[cur][1].z, Af[cur][1].w);
#pragma unroll
        for (int ct = 0; ct < 12; ++ct)
            acc[ct] = MFMAH(af.v, Bf[cur][ct], acc[ct]);
    }

    // ---- split-K combine ----
    if (kh == 1) {
#pragma unroll
        for (int ct = 0; ct < 12; ++ct)
            *(f32x4*)&comb[rt][(ct * 64 + lane) * 4] = acc[ct];
    }
    __syncthreads();
    if (kh == 0) {
#pragma unroll
        for (int ct = 0; ct < 12; ++ct) {
            f32x4 o = *(const f32x4*)&comb[rt][(ct * 64 + lane) * 4];
            acc[ct].x += o.x; acc[ct].y += o.y; acc[ct].z += o.z; acc[ct].w += o.w;
        }
#pragma unroll
        for (int ct = 0; ct < 12; ++ct) {
            const int cg = ct * 16 + q15;
            float vals[4] = {acc[ct].x, acc[ct].y, acc[ct].z, acc[ct].w};
#pragma unroll
            for (int r = 0; r < 4; ++r) {
                const int n = gr0 + rt * 16 + quad * 4 + r;
                if (cg < 64) {
                    Qw[(size_t)n * 64 + cg] = f2h(vals[r]);
                } else if (cg < 128) {
                    const int d = cg - 64;
                    Kt[(size_t)(n >> 4) * 1024 + (d >> 5) * 512 +
                       ((d >> 3) & 3) * 128 + (n & 15) * 8 + (d & 7)] = f2h(vals[r]);
                } else {
                    const int d = cg - 128;
                    Vt[(size_t)(n >> 5) * 2048 + (d >> 4) * 512 +
                       ((n >> 3) & 3) * 128 + (d & 15) * 8 + (n & 7)] = f2h(vals[r]);
                }
            }
        }
    }
}

// ---------------------------------------------------------------------------
// Kernel 2: f16 MFMA flash attention. grid 256 x 512 (1 block/CU, 2 w/SIMD).
// Block = 64 queries; wave w owns j in [w*512, +512) = 16 iters of 32 keys.
// K/V fragments loaded DIRECTLY from global (contiguous 1KB per instr via
// frag-tiled layouts); K register-dbuf, V same-iter. LDS only for P strips
// and the 8-way o/l tree combine. No-max exp2 softmax.
// ---------------------------------------------------------------------------
__global__ __launch_bounds__(512, 2) void attn(
    const ushort* __restrict__ Qw, const ushort* __restrict__ Kt,
    const ushort* __restrict__ Vt, float* __restrict__ out)
{
    // floats [0,16384): combine bufs (4 x 4096); aliased by P strips during
    // the loop (shorts [0, 8*2560)). floats [16384,16896): l per wave.
    __shared__ __align__(16) float aF[16896];   // 67584 B
    short* aS = (short*)aF;

    const int t    = threadIdx.x;
    const int lane = t & 63;
    const int w    = __builtin_amdgcn_readfirstlane(t >> 6);
    const int q15  = lane & 15, quad = lane >> 4;

    const int bb    = blockIdx.x;
    const int xcd   = bb & 7;
    const int batch = xcd >> 1;
    const int slot  = (bb >> 3) | ((xcd & 1) << 5);   // 0..63
    const int q0    = slot * 64;
    const size_t base = (size_t)batch * SEQ;

    // Q fragments [g][h] for the block's 64 queries, resident all kernel
    f16x8 qf[4][2];
#pragma unroll
    for (int g = 0; g < 4; ++g)
#pragma unroll
        for (int h = 0; h < 2; ++h)
            qf[g][h] = *(const f16x8*)(Qw + (base + q0 + g * 16 + q15) * 64 + h * 32 + quad * 8);

    f32x4 oacc[4][4];
#pragma unroll
    for (int g = 0; g < 4; ++g)
#pragma unroll
        for (int dt = 0; dt < 4; ++dt) oacc[g][dt] = (f32x4){0.f, 0.f, 0.f, 0.f};
    float lsum[4] = {0.f, 0.f, 0.f, 0.f};

    // fragment source pointers (lane*8 encodes quad*128+q15*8 in both layouts)
    const size_t j0g = base + w * 512;                  // global first key
    const ushort* Kfb = Kt + (j0g >> 4) * 1024 + lane * 8;
    const ushort* Vfb = Vt + (j0g >> 5) * 2048 + lane * 8;
    short* Ps = aS + w * 2560;                          // [64 q][40]

    f16x8 kf[2][2][2];   // [buf][jt][h]
#pragma unroll
    for (int jt = 0; jt < 2; ++jt)
#pragma unroll
        for (int h = 0; h < 2; ++h)
            kf[0][jt][h] = *(const f16x8*)(Kfb + jt * 1024 + h * 512);

#pragma unroll 2
    for (int it = 0; it < 16; ++it) {
        const int cur = it & 1, nxt = cur ^ 1;
        if (it < 15) {   // K prefetch for it+1 (2 j16-tiles ahead)
#pragma unroll
            for (int jt = 0; jt < 2; ++jt)
#pragma unroll
                for (int h = 0; h < 2; ++h)
                    kf[nxt][jt][h] = *(const f16x8*)(Kfb + (size_t)(it + 1) * 2048 + jt * 1024 + h * 512);
        }
        // V fragments for THIS iter (consumed after softmax -> latency hidden)
        f16x8 vf[4];
#pragma unroll
        for (int dt = 0; dt < 4; ++dt)
            vf[dt] = *(const f16x8*)(Vfb + (size_t)it * 2048 + dt * 512);

        // QK^T: lane holds q = g*16+q15 (col), j = jt*16+quad*4+r (row)
#pragma unroll
        for (int g = 0; g < 4; ++g) {
#pragma unroll
            for (int jt = 0; jt < 2; ++jt) {
                f32x4 z = (f32x4){0.f, 0.f, 0.f, 0.f};
                z = MFMAH(kf[cur][jt][0], qf[g][0], z);
                z = MFMAH(kf[cur][jt][1], qf[g][1], z);
                float e0 = exp2f(z.x), e1 = exp2f(z.y);
                float e2 = exp2f(z.z), e3 = exp2f(z.w);
                lsum[g] += (e0 + e1) + (e2 + e3);
                uint2 pk = make_uint2(pkrtz(e0, e1), pkrtz(e2, e3));
                *(uint2*)(Ps + (g * 16 + q15) * 40 + jt * 16 + quad * 4) = pk;
            }
        }

        // P A-fragments (wave-synchronous LDS round-trip) + PV
        f16x8 pf[4];
#pragma unroll
        for (int g = 0; g < 4; ++g)
            pf[g] = *(const f16x8*)(Ps + (g * 16 + q15) * 40 + quad * 8);
#pragma unroll
        for (int dt = 0; dt < 4; ++dt)
#pragma unroll
            for (int g = 0; g < 4; ++g)
                oacc[g][dt] = MFMAH(pf[g], vf[dt], oacc[g][dt]);
    }

    // ---- l: quad-reduce, publish per wave ----
#pragma unroll
    for (int g = 0; g < 4; ++g) {
        lsum[g] += __shfl_xor(lsum[g], 16);
        lsum[g] += __shfl_xor(lsum[g], 32);
    }
    if (quad == 0) {
#pragma unroll
        for (int g = 0; g < 4; ++g)
            aF[16384 + w * 64 + g * 16 + q15] = lsum[g];
    }
    __syncthreads();   // P strips dead; l published; combine bufs usable

    // ---- 8-way tree combine of o through LDS ----
    // owrite/oadd: lane value (g,dt,r) <-> q = g*16+quad*4+r, d = dt*16+q15
#define OWRITE(idx)                                                          \
    {                                                                        \
        float* b = aF + (idx) * 4096;                                        \
        _Pragma("unroll") for (int g = 0; g < 4; ++g)                        \
        _Pragma("unroll") for (int dt = 0; dt < 4; ++dt) {                   \
            b[(g * 16 + quad * 4 + 0) * 64 + dt * 16 + q15] = oacc[g][dt].x; \
            b[(g * 16 + quad * 4 + 1) * 64 + dt * 16 + q15] = oacc[g][dt].y; \
            b[(g * 16 + quad * 4 + 2) * 64 + dt * 16 + q15] = oacc[g][dt].z; \
            b[(g * 16 + quad * 4 + 3) * 64 + dt * 16 + q15] = oacc[g][dt].w; \
        }                                                                    \
    }
#define OADD(idx)                                                            \
    {                                                                        \
        const float* b = aF + (idx) * 4096;                                  \
        _Pragma("unroll") for (int g = 0; g < 4; ++g)                        \
        _Pragma("unroll") for (int dt = 0; dt < 4; ++dt) {                   \
            oacc[g][dt].x += b[(g * 16 + quad * 4 + 0) * 64 + dt * 16 + q15];\
            oacc[g][dt].y += b[(g * 16 + quad * 4 + 1) * 64 + dt * 16 + q15];\
            oacc[g][dt].z += b[(g * 16 + quad * 4 + 2) * 64 + dt * 16 + q15];\
            oacc[g][dt].w += b[(g * 16 + quad * 4 + 3) * 64 + dt * 16 + q15];\
        }                                                                    \
    }
    if (w >= 4) OWRITE(w - 4);
    __syncthreads();
    if (w < 4) OADD(w);
    __syncthreads();
    if (w == 2 || w == 3) OWRITE(w - 2);
    __syncthreads();
    if (w < 2) OADD(w);
    __syncthreads();
    if (w < 2) OWRITE(w);
    __syncthreads();

    // ---- final: all 512 threads normalize + store ----
    {
        const int q  = t >> 3;            // 0..63
        const int d0 = (t & 7) * 8;
        float l = 0.f;
#pragma unroll
        for (int i = 0; i < 8; ++i) l += aF[16384 + i * 64 + q];
        const float linv = 1.0f / l;
#pragma unroll
        for (int k2 = 0; k2 < 2; ++k2) {
            float4 a = *(const float4*)&aF[q * 64 + d0 + k2 * 4];
            float4 b = *(const float4*)&aF[4096 + q * 64 + d0 + k2 * 4];
            float4 s;
            s.x = (a.x + b.x) * linv; s.y = (a.y + b.y) * linv;
            s.z = (a.z + b.z) * linv; s.w = (a.w + b.w) * linv;
            *(float4*)(out + (base + q0 + q) * 64 + d0 + k2 * 4) = s;
        }
    }
}

// ---------------------------------------------------------------------------
extern "C" void kernel_launch(void* const* d_in, const int* in_sizes, int n_in,
                              void* d_out, int out_size, void* d_ws, size_t ws_size,
                              hipStream_t stream)
{
    const float* ix = (const float*)d_in[0];
    const float* Wk = (const float*)d_in[1];
    const float* Wq = (const float*)d_in[2];
    const float* Wv = (const float*)d_in[3];
    float* out = (float*)d_out;

    // ws: Qw | Kt | Vt (NROW*64 ushorts each) + WTt (24*192*32 ushorts)
    ushort* Qw  = (ushort*)d_ws;
    ushort* Kt  = Qw + (size_t)NROW * Hm;
    ushort* Vt  = Kt + (size_t)NROW * Hm;
    ushort* WTt = Vt + (size_t)NROW * Hm;

    wconv<<<192, 256, 0, stream>>>(Wq, Wk, Wv, WTt);
    proj<<<512, 256, 0, stream>>>(ix, WTt, Qw, Kt, Vt);
    attn<<<256, 512, 0, stream>>>(Qw, Kt, Vt, out);
}

// Round 7
// 250.499 us; speedup vs baseline: 1.0065x; 1.0065x over previous
//
#include <hip/hip_runtime.h>
#include <math.h>

#define Dm   768
#define Hm   64
#define SEQ  4096
#define NB   4
#define NROW (NB * SEQ)

// scale 1/sqrt(64) and log2(e) folded into Wq at wconv time -> exp2 domain
#define QSCALE (0.125f * 1.4426950408889634f)

typedef _Float16 f16;
typedef __attribute__((ext_vector_type(8))) _Float16 f16x8;
typedef __attribute__((ext_vector_type(2))) __fp16 fp16x2_raw;
typedef __attribute__((ext_vector_type(4))) float f32x4;
typedef unsigned int uint;
typedef unsigned short ushort;

#define MFMAH(A, B, C) __builtin_amdgcn_mfma_f32_16x16x32_f16(A, B, C, 0, 0, 0)

__device__ __forceinline__ uint pkrtz(float a, float b) {
    fp16x2_raw r = __builtin_amdgcn_cvt_pkrtz(a, b);
    return __builtin_bit_cast(uint, r);
}
__device__ __forceinline__ ushort f2h(float f) {
    f16 h = (f16)f;
    return __builtin_bit_cast(ushort, h);
}
union F16x8U { uint u[4]; f16x8 v; };

// ---------------------------------------------------------------------------
// Kernel 0: W -> WTt f16, tiled [kt(24)][c(192)][kk(32)] so proj B-fragment
// loads are coalesced 1KB/instr. c: 0-63 Q (QSCALE folded), 64-127 K,
// 128-191 V. Stores are 64B-contiguous runs (clean).
// ---------------------------------------------------------------------------
__global__ __launch_bounds__(256) void wconv(
    const float* __restrict__ Wq, const float* __restrict__ Wk,
    const float* __restrict__ Wv, ushort* __restrict__ WTt)
{
    const int c   = blockIdx.x;
    const int mat = c >> 6, col = c & 63;
    const float* W = (mat == 0) ? Wq : (mat == 1 ? Wk : Wv);
    const float sc = (mat == 0) ? QSCALE : 1.0f;
    for (int k = threadIdx.x; k < Dm; k += 256)
        WTt[((size_t)(k >> 5) * 192 + c) * 32 + (k & 31)] = f2h(W[k * 64 + col] * sc);
}

// ---------------------------------------------------------------------------
// Kernel 1: f16 MFMA QKV projection, LDS-free main loop, split-K=2.
// grid 512 x 256 (2 blocks/CU, 2 waves/SIMD). Block = 32 rows.
// Wave (rt = w&1, kh = w>>1): rows gr0+rt*16.., k in [kh*384, +384) = 12 iters.
// A: ix fp32 -> registers (2 dwordx4/iter) -> pkrtz. B: WTt coalesced frags,
// register-dbuf. 12 MFMA/iter. Split-K combine through LDS.
// Epilogue (ALL stores >=32B-contiguous per lane-group):
//   Qw row-major scalar (32B runs); Kt[j>>4][k>>4][j&15][k&15] scalar
//   (32B runs); Vt[n>>5][d>>4][(n>>3)&3][d&15][n&7] as ushort4.
// ---------------------------------------------------------------------------
__global__ __launch_bounds__(256) void proj(
    const float* __restrict__ ix, const ushort* __restrict__ WTt,
    ushort* __restrict__ Qw, ushort* __restrict__ Kt, ushort* __restrict__ Vt)
{
    __shared__ __align__(16) float comb[2][3072];   // 24 KiB

    const int t    = threadIdx.x;
    const int lane = t & 63;
    const int w    = __builtin_amdgcn_readfirstlane(t >> 6);
    const int rt   = w & 1, kh = w >> 1;
    const int q15  = lane & 15, quad = lane >> 4;
    const int gr0  = blockIdx.x * 32;
    const int row  = gr0 + rt * 16 + q15;

    const float*  Ab = ix + (size_t)row * Dm + kh * 384 + quad * 8;
    const ushort* Bb = WTt + ((size_t)(kh * 12) * 192 + q15) * 32 + quad * 8;

    f32x4 acc[12];
#pragma unroll
    for (int ct = 0; ct < 12; ++ct) acc[ct] = (f32x4){0.f, 0.f, 0.f, 0.f};

    f32x4 Af[2][2];
    f16x8 Bf[2][12];
    Af[0][0] = *(const f32x4*)(Ab);
    Af[0][1] = *(const f32x4*)(Ab + 4);
#pragma unroll
    for (int ct = 0; ct < 12; ++ct)
        Bf[0][ct] = *(const f16x8*)(Bb + ct * 512);

#pragma unroll 2
    for (int it = 0; it < 12; ++it) {
        const int cur = it & 1, nxt = cur ^ 1;
        if (it < 11) {
            Af[nxt][0] = *(const f32x4*)(Ab + (it + 1) * 32);
            Af[nxt][1] = *(const f32x4*)(Ab + (it + 1) * 32 + 4);
#pragma unroll
            for (int ct = 0; ct < 12; ++ct)
                Bf[nxt][ct] = *(const f16x8*)(Bb + (size_t)(it + 1) * 6144 + ct * 512);
        }
        F16x8U af;
        af.u[0] = pkrtz(Af[cur][0].x, Af[cur][0].y);
        af.u[1] = pkrtz(Af[cur][0].z, Af[cur][0].w);
        af.u[2] = pkrtz(Af[cur][1].x, Af[cur][1].y);
        af.u[3] = pkrtz(Af[cur][1].z, Af[cur][1].w);
#pragma unroll
        for (int ct = 0; ct < 12; ++ct)
            acc[ct] = MFMAH(af.v, Bf[cur][ct], acc[ct]);
    }

    // ---- split-K combine ----
    if (kh == 1) {
#pragma unroll
        for (int ct = 0; ct < 12; ++ct)
            *(f32x4*)&comb[rt][(ct * 64 + lane) * 4] = acc[ct];
    }
    __syncthreads();
    if (kh == 0) {
#pragma unroll
        for (int ct = 0; ct < 12; ++ct) {
            f32x4 o = *(const f32x4*)&comb[rt][(ct * 64 + lane) * 4];
            acc[ct].x += o.x; acc[ct].y += o.y; acc[ct].z += o.z; acc[ct].w += o.w;
        }
        const int n4  = (gr0 >> 4) + rt;   // n>>4 for Kt
        const int j32 = gr0 >> 5;          // n>>5 for Vt
#pragma unroll
        for (int ct = 0; ct < 12; ++ct) {
            float vals[4] = {acc[ct].x, acc[ct].y, acc[ct].z, acc[ct].w};
            if (ct < 4) {                       // Q: row-major, 32B runs
#pragma unroll
                for (int r = 0; r < 4; ++r)
                    Qw[(size_t)(gr0 + rt * 16 + quad * 4 + r) * 64 + ct * 16 + q15] = f2h(vals[r]);
            } else if (ct < 8) {                // K tiled: [j>>4][k>>4][j&15][k&15]
#pragma unroll
                for (int r = 0; r < 4; ++r)
                    Kt[(size_t)n4 * 1024 + (ct - 4) * 256 + (quad * 4 + r) * 16 + q15] = f2h(vals[r]);
            } else {                            // V tiled, ushort4 (8B) stores
                ushort4 vv;
                vv.x = f2h(vals[0]); vv.y = f2h(vals[1]);
                vv.z = f2h(vals[2]); vv.w = f2h(vals[3]);
                *(ushort4*)(Vt + (size_t)j32 * 2048 + (ct - 8) * 512 +
                            (rt * 2 + (quad >> 1)) * 128 + q15 * 8 + (quad & 1) * 4) = vv;
            }
        }
    }
}

// ---------------------------------------------------------------------------
// Kernel 2: f16 MFMA flash attention. grid 256 x 512 (1 block/CU, 2 w/SIMD).
// Block = 64 queries; wave w owns j in [w*512, +512) = 16 iters of 32 keys.
// K AND V fragments register-double-buffered directly from global (1KB
// contiguous per instr via tiled layouts). LDS only for P strips + the
// 8-way o/l tree combine. No-max exp2 softmax.
// ---------------------------------------------------------------------------
__global__ __launch_bounds__(512, 2) void attn(
    const ushort* __restrict__ Qw, const ushort* __restrict__ Kt,
    const ushort* __restrict__ Vt, float* __restrict__ out)
{
    // floats [0,16384): combine bufs (4 x 4096), aliased by P strips during
    // the loop (shorts [0, 8*2560)). floats [16384,16896): l per wave.
    __shared__ __align__(16) float aF[16896];   // 67584 B
    short* aS = (short*)aF;

    const int t    = threadIdx.x;
    const int lane = t & 63;
    const int w    = __builtin_amdgcn_readfirstlane(t >> 6);
    const int q15  = lane & 15, quad = lane >> 4;

    const int bb    = blockIdx.x;
    const int xcd   = bb & 7;
    const int batch = xcd >> 1;
    const int slot  = (bb >> 3) | ((xcd & 1) << 5);   // 0..63
    const int q0    = slot * 64;
    const size_t base = (size_t)batch * SEQ;

    // Q fragments [g][h], resident all kernel
    f16x8 qf[4][2];
#pragma unroll
    for (int g = 0; g < 4; ++g)
#pragma unroll
        for (int h = 0; h < 2; ++h)
            qf[g][h] = *(const f16x8*)(Qw + (base + q0 + g * 16 + q15) * 64 + h * 32 + quad * 8);

    f32x4 oacc[4][4];
#pragma unroll
    for (int g = 0; g < 4; ++g)
#pragma unroll
        for (int dt = 0; dt < 4; ++dt) oacc[g][dt] = (f32x4){0.f, 0.f, 0.f, 0.f};
    float lsum[4] = {0.f, 0.f, 0.f, 0.f};

    // fragment source pointers
    const size_t j0g = base + w * 512;                  // wave's first key
    const ushort* Kfb = Kt + (j0g >> 4) * 1024;
    const ushort* Vfb = Vt + (j0g >> 5) * 2048 + lane * 8;
    short* Ps = aS + w * 2560;                          // [64 q][40]

    // lane-const K-frag offsets: j=jt*16+q15, k(d)=32h+quad*8
    int koff[2][2];
#pragma unroll
    for (int jt = 0; jt < 2; ++jt)
#pragma unroll
        for (int h = 0; h < 2; ++h)
            koff[jt][h] = jt * 1024 + h * 512 + (quad >> 1) * 256 + q15 * 16 + (quad & 1) * 8;

    f16x8 kf[2][2][2], vf[2][4];
#pragma unroll
    for (int jt = 0; jt < 2; ++jt)
#pragma unroll
        for (int h = 0; h < 2; ++h)
            kf[0][jt][h] = *(const f16x8*)(Kfb + koff[jt][h]);
#pragma unroll
    for (int dt = 0; dt < 4; ++dt)
        vf[0][dt] = *(const f16x8*)(Vfb + dt * 512);

#pragma unroll 2
    for (int it = 0; it < 16; ++it) {
        const int cur = it & 1, nxt = cur ^ 1;
        if (it < 15) {   // prefetch K AND V for it+1 (full iter of latency)
#pragma unroll
            for (int jt = 0; jt < 2; ++jt)
#pragma unroll
                for (int h = 0; h < 2; ++h)
                    kf[nxt][jt][h] = *(const f16x8*)(Kfb + (size_t)(it + 1) * 2048 + koff[jt][h]);
#pragma unroll
            for (int dt = 0; dt < 4; ++dt)
                vf[nxt][dt] = *(const f16x8*)(Vfb + (size_t)(it + 1) * 2048 + dt * 512);
        }

        // QK^T: lane holds q = g*16+q15 (col), j = jt*16+quad*4+r (row)
#pragma unroll
        for (int g = 0; g < 4; ++g) {
#pragma unroll
            for (int jt = 0; jt < 2; ++jt) {
                f32x4 z = (f32x4){0.f, 0.f, 0.f, 0.f};
                z = MFMAH(kf[cur][jt][0], qf[g][0], z);
                z = MFMAH(kf[cur][jt][1], qf[g][1], z);
                float e0 = exp2f(z.x), e1 = exp2f(z.y);
                float e2 = exp2f(z.z), e3 = exp2f(z.w);
                lsum[g] += (e0 + e1) + (e2 + e3);
                uint2 pk = make_uint2(pkrtz(e0, e1), pkrtz(e2, e3));
                *(uint2*)(Ps + (g * 16 + q15) * 40 + jt * 16 + quad * 4) = pk;
            }
        }

        // P A-fragments (wave-synchronous LDS round-trip) + PV
        f16x8 pf[4];
#pragma unroll
        for (int g = 0; g < 4; ++g)
            pf[g] = *(const f16x8*)(Ps + (g * 16 + q15) * 40 + quad * 8);
#pragma unroll
        for (int dt = 0; dt < 4; ++dt)
#pragma unroll
            for (int g = 0; g < 4; ++g)
                oacc[g][dt] = MFMAH(pf[g], vf[cur][dt], oacc[g][dt]);
    }

    // ---- l: quad-reduce, publish per wave ----
#pragma unroll
    for (int g = 0; g < 4; ++g) {
        lsum[g] += __shfl_xor(lsum[g], 16);
        lsum[g] += __shfl_xor(lsum[g], 32);
    }
    if (quad == 0) {
#pragma unroll
        for (int g = 0; g < 4; ++g)
            aF[16384 + w * 64 + g * 16 + q15] = lsum[g];
    }
    __syncthreads();   // P strips dead; l published; combine bufs usable

    // ---- 8-way tree combine of o through LDS ----
#define OWRITE(idx)                                                          \
    {                                                                        \
        float* b = aF + (idx) * 4096;                                        \
        _Pragma("unroll") for (int g = 0; g < 4; ++g)                        \
        _Pragma("unroll") for (int dt = 0; dt < 4; ++dt) {                   \
            b[(g * 16 + quad * 4 + 0) * 64 + dt * 16 + q15] = oacc[g][dt].x; \
            b[(g * 16 + quad * 4 + 1) * 64 + dt * 16 + q15] = oacc[g][dt].y; \
            b[(g * 16 + quad * 4 + 2) * 64 + dt * 16 + q15] = oacc[g][dt].z; \
            b[(g * 16 + quad * 4 + 3) * 64 + dt * 16 + q15] = oacc[g][dt].w; \
        }                                                                    \
    }
#define OADD(idx)                                                            \
    {                                                                        \
        const float* b = aF + (idx) * 4096;                                  \
        _Pragma("unroll") for (int g = 0; g < 4; ++g)                        \
        _Pragma("unroll") for (int dt = 0; dt < 4; ++dt) {                   \
            oacc[g][dt].x += b[(g * 16 + quad * 4 + 0) * 64 + dt * 16 + q15];\
            oacc[g][dt].y += b[(g * 16 + quad * 4 + 1) * 64 + dt * 16 + q15];\
            oacc[g][dt].z += b[(g * 16 + quad * 4 + 2) * 64 + dt * 16 + q15];\
            oacc[g][dt].w += b[(g * 16 + quad * 4 + 3) * 64 + dt * 16 + q15];\
        }                                                                    \
    }
    if (w >= 4) OWRITE(w - 4);
    __syncthreads();
    if (w < 4) OADD(w);
    __syncthreads();
    if (w == 2 || w == 3) OWRITE(w - 2);
    __syncthreads();
    if (w < 2) OADD(w);
    __syncthreads();
    if (w < 2) OWRITE(w);
    __syncthreads();

    // ---- final: all 512 threads normalize + store ----
    {
        const int q  = t >> 3;            // 0..63
        const int d0 = (t & 7) * 8;
        float l = 0.f;
#pragma unroll
        for (int i = 0; i < 8; ++i) l += aF[16384 + i * 64 + q];
        const float linv = 1.0f / l;
#pragma unroll
        for (int k2 = 0; k2 < 2; ++k2) {
            float4 a = *(const float4*)&aF[q * 64 + d0 + k2 * 4];
            float4 b = *(const float4*)&aF[4096 + q * 64 + d0 + k2 * 4];
            float4 s;
            s.x = (a.x + b.x) * linv; s.y = (a.y + b.y) * linv;
            s.z = (a.z + b.z) * linv; s.w = (a.w + b.w) * linv;
            *(float4*)(out + (base + q0 + q) * 64 + d0 + k2 * 4) = s;
        }
    }
}

// ---------------------------------------------------------------------------
extern "C" void kernel_launch(void* const* d_in, const int* in_sizes, int n_in,
                              void* d_out, int out_size, void* d_ws, size_t ws_size,
                              hipStream_t stream)
{
    const float* ix = (const float*)d_in[0];
    const float* Wk = (const float*)d_in[1];
    const float* Wq = (const float*)d_in[2];
    const float* Wv = (const float*)d_in[3];
    float* out = (float*)d_out;

    // ws: Qw | Kt | Vt (NROW*64 ushorts each) + WTt (24*192*32 ushorts)
    ushort* Qw  = (ushort*)d_ws;
    ushort* Kt  = Qw + (size_t)NROW * Hm;
    ushort* Vt  = Kt + (size_t)NROW * Hm;
    ushort* WTt = Vt + (size_t)NROW * Hm;

    wconv<<<192, 256, 0, stream>>>(Wq, Wk, Wv, WTt);
    proj<<<512, 256, 0, stream>>>(ix, WTt, Qw, Kt, Vt);
    attn<<<256, 512, 0, stream>>>(Qw, Kt, Vt, out);
}

// Round 8
// 135.910 us; speedup vs baseline: 1.8551x; 1.8431x over previous
//
#include <hip/hip_runtime.h>
#include <math.h>

#define Dm   768
#define Hm   64
#define SEQ  4096
#define NB   4
#define NROW (NB * SEQ)

// scale 1/sqrt(64) and log2(e) folded into Wq at wconv time -> exp2 domain
#define QSCALE (0.125f * 1.4426950408889634f)

typedef _Float16 f16;
typedef __attribute__((ext_vector_type(8))) _Float16 f16x8;
typedef __attribute__((ext_vector_type(2))) __fp16 fp16x2_raw;
typedef __attribute__((ext_vector_type(4))) float f32x4;
typedef unsigned int uint;
typedef unsigned short ushort;

#define MFMAH(A, B, C) __builtin_amdgcn_mfma_f32_16x16x32_f16(A, B, C, 0, 0, 0)

__device__ __forceinline__ uint pkrtz(float a, float b) {
    fp16x2_raw r = __builtin_amdgcn_cvt_pkrtz(a, b);
    return __builtin_bit_cast(uint, r);
}
__device__ __forceinline__ ushort f2h(float f) {
    f16 h = (f16)f;
    return __builtin_bit_cast(ushort, h);
}
union F16x8U { uint u[4]; f16x8 v; };

// ---------------------------------------------------------------------------
// Kernel 0: W -> WTt f16, tiled [kt(24)][c(192)][kk(32)] so proj B-fragment
// loads are coalesced 1KB/instr. c: 0-63 Q (QSCALE folded), 64-127 K,
// 128-191 V.
// ---------------------------------------------------------------------------
__global__ __launch_bounds__(256) void wconv(
    const float* __restrict__ Wq, const float* __restrict__ Wk,
    const float* __restrict__ Wv, ushort* __restrict__ WTt)
{
    const int c   = blockIdx.x;
    const int mat = c >> 6, col = c & 63;
    const float* W = (mat == 0) ? Wq : (mat == 1 ? Wk : Wv);
    const float sc = (mat == 0) ? QSCALE : 1.0f;
    for (int k = threadIdx.x; k < Dm; k += 256)
        WTt[((size_t)(k >> 5) * 192 + c) * 32 + (k & 31)] = f2h(W[k * 64 + col] * sc);
}

// ---------------------------------------------------------------------------
// Kernel 1: f16 MFMA QKV projection, LDS-free main loop, split-K=2.
// grid 512 x 256 (2 blocks/CU). Block = 32 rows. Wave (rt=w&1, kh=w>>1):
// rows gr0+rt*16.., k in [kh*384, +384) = 12 iters of 32.
// B: SINGLE-buffered 12 frags/iter from L2-hot WTt, issued FIRST each iter
//    (one live set = 48 VGPRs -- the R6/R7 dbuf spilled to scratch: 301 MB
//    phantom WRITE_SIZE, 143 us. Do NOT register-double-buffer B.)
// A: ix fp32 -> registers, depth-1 dbuf (aggregate in-flight 16KB/CU > BDP).
// Split-K combine through LDS. Epilogue unchanged from R7 (correct, clean).
// ---------------------------------------------------------------------------
__global__ __launch_bounds__(256) void proj(
    const float* __restrict__ ix, const ushort* __restrict__ WTt,
    ushort* __restrict__ Qw, ushort* __restrict__ Kt, ushort* __restrict__ Vt)
{
    __shared__ __align__(16) float comb[2][3072];   // 24 KiB

    const int t    = threadIdx.x;
    const int lane = t & 63;
    const int w    = __builtin_amdgcn_readfirstlane(t >> 6);
    const int rt   = w & 1, kh = w >> 1;
    const int q15  = lane & 15, quad = lane >> 4;
    const int gr0  = blockIdx.x * 32;
    const int row  = gr0 + rt * 16 + q15;

    const float*  Ab = ix + (size_t)row * Dm + kh * 384 + quad * 8;
    const ushort* Bb = WTt + ((size_t)(kh * 12) * 192 + q15) * 32 + quad * 8;

    f32x4 acc[12];
#pragma unroll
    for (int ct = 0; ct < 12; ++ct) acc[ct] = (f32x4){0.f, 0.f, 0.f, 0.f};

    f32x4 Af[2][2];
    Af[0][0] = *(const f32x4*)(Ab);
    Af[0][1] = *(const f32x4*)(Ab + 4);

#pragma unroll 2
    for (int it = 0; it < 12; ++it) {
        const int cur = it & 1, nxt = cur ^ 1;

        // B loads first (L2-hot, single buffer, one live set)
        f16x8 Bf[12];
#pragma unroll
        for (int ct = 0; ct < 12; ++ct)
            Bf[ct] = *(const f16x8*)(Bb + (size_t)it * 6144 + ct * 512);

        // A prefetch for next iter (HBM) -- issued AFTER B so B-consuming
        // MFMAs don't wait on HBM-latency loads
        if (it < 11) {
            Af[nxt][0] = *(const f32x4*)(Ab + (it + 1) * 32);
            Af[nxt][1] = *(const f32x4*)(Ab + (it + 1) * 32 + 4);
        }

        F16x8U af;
        af.u[0] = pkrtz(Af[cur][0].x, Af[cur][0].y);
        af.u[1] = pkrtz(Af[cur][0].z, Af[cur][0].w);
        af.u[2] = pkrtz(Af[cur][1].x, Af[cur][1].y);
        af.u[3] = pkrtz(Af[cur][1].z, Af[cur][1].w);
#pragma unroll
        for (int ct = 0; ct < 12; ++ct)
            acc[ct] = MFMAH(af.v, Bf[ct], acc[ct]);
    }

    // ---- split-K combine ----
    if (kh == 1) {
#pragma unroll
        for (int ct = 0; ct < 12; ++ct)
            *(f32x4*)&comb[rt][(ct * 64 + lane) * 4] = acc[ct];
    }
    __syncthreads();
    if (kh == 0) {
#pragma unroll
        for (int ct = 0; ct < 12; ++ct) {
            f32x4 o = *(const f32x4*)&comb[rt][(ct * 64 + lane) * 4];
            acc[ct].x += o.x; acc[ct].y += o.y; acc[ct].z += o.z; acc[ct].w += o.w;
        }
        const int n4  = (gr0 >> 4) + rt;   // n>>4 for Kt
        const int j32 = gr0 >> 5;          // n>>5 for Vt
#pragma unroll
        for (int ct = 0; ct < 12; ++ct) {
            float vals[4] = {acc[ct].x, acc[ct].y, acc[ct].z, acc[ct].w};
            if (ct < 4) {                       // Q: row-major, 32B runs
#pragma unroll
                for (int r = 0; r < 4; ++r)
                    Qw[(size_t)(gr0 + rt * 16 + quad * 4 + r) * 64 + ct * 16 + q15] = f2h(vals[r]);
            } else if (ct < 8) {                // K tiled: [j>>4][k>>4][j&15][k&15]
#pragma unroll
                for (int r = 0; r < 4; ++r)
                    Kt[(size_t)n4 * 1024 + (ct - 4) * 256 + (quad * 4 + r) * 16 + q15] = f2h(vals[r]);
            } else {                            // V tiled, ushort4 (8B) stores
                ushort4 vv;
                vv.x = f2h(vals[0]); vv.y = f2h(vals[1]);
                vv.z = f2h(vals[2]); vv.w = f2h(vals[3]);
                *(ushort4*)(Vt + (size_t)j32 * 2048 + (ct - 8) * 512 +
                            (rt * 2 + (quad >> 1)) * 128 + q15 * 8 + (quad & 1) * 4) = vv;
            }
        }
    }
}

// ---------------------------------------------------------------------------
// Kernel 2: f16 MFMA flash attention. grid 256 x 512 (1 block/CU, 2 w/SIMD).
// Block = 64 queries; wave w owns j in [w*512, +512) = 16 iters of 32 keys.
// K AND V fragments register-double-buffered directly from global (1KB
// contiguous per instr via tiled layouts). LDS only for P strips + the
// 8-way o/l tree combine. No-max exp2 softmax.  (unchanged from R7)
// ---------------------------------------------------------------------------
__global__ __launch_bounds__(512, 2) void attn(
    const ushort* __restrict__ Qw, const ushort* __restrict__ Kt,
    const ushort* __restrict__ Vt, float* __restrict__ out)
{
    __shared__ __align__(16) float aF[16896];   // 67584 B
    short* aS = (short*)aF;

    const int t    = threadIdx.x;
    const int lane = t & 63;
    const int w    = __builtin_amdgcn_readfirstlane(t >> 6);
    const int q15  = lane & 15, quad = lane >> 4;

    const int bb    = blockIdx.x;
    const int xcd   = bb & 7;
    const int batch = xcd >> 1;
    const int slot  = (bb >> 3) | ((xcd & 1) << 5);   // 0..63
    const int q0    = slot * 64;
    const size_t base = (size_t)batch * SEQ;

    f16x8 qf[4][2];
#pragma unroll
    for (int g = 0; g < 4; ++g)
#pragma unroll
        for (int h = 0; h < 2; ++h)
            qf[g][h] = *(const f16x8*)(Qw + (base + q0 + g * 16 + q15) * 64 + h * 32 + quad * 8);

    f32x4 oacc[4][4];
#pragma unroll
    for (int g = 0; g < 4; ++g)
#pragma unroll
        for (int dt = 0; dt < 4; ++dt) oacc[g][dt] = (f32x4){0.f, 0.f, 0.f, 0.f};
    float lsum[4] = {0.f, 0.f, 0.f, 0.f};

    const size_t j0g = base + w * 512;
    const ushort* Kfb = Kt + (j0g >> 4) * 1024;
    const ushort* Vfb = Vt + (j0g >> 5) * 2048 + lane * 8;
    short* Ps = aS + w * 2560;                          // [64 q][40]

    int koff[2][2];
#pragma unroll
    for (int jt = 0; jt < 2; ++jt)
#pragma unroll
        for (int h = 0; h < 2; ++h)
            koff[jt][h] = jt * 1024 + h * 512 + (quad >> 1) * 256 + q15 * 16 + (quad & 1) * 8;

    f16x8 kf[2][2][2], vf[2][4];
#pragma unroll
    for (int jt = 0; jt < 2; ++jt)
#pragma unroll
        for (int h = 0; h < 2; ++h)
            kf[0][jt][h] = *(const f16x8*)(Kfb + koff[jt][h]);
#pragma unroll
    for (int dt = 0; dt < 4; ++dt)
        vf[0][dt] = *(const f16x8*)(Vfb + dt * 512);

#pragma unroll 2
    for (int it = 0; it < 16; ++it) {
        const int cur = it & 1, nxt = cur ^ 1;
        if (it < 15) {
#pragma unroll
            for (int jt = 0; jt < 2; ++jt)
#pragma unroll
                for (int h = 0; h < 2; ++h)
                    kf[nxt][jt][h] = *(const f16x8*)(Kfb + (size_t)(it + 1) * 2048 + koff[jt][h]);
#pragma unroll
            for (int dt = 0; dt < 4; ++dt)
                vf[nxt][dt] = *(const f16x8*)(Vfb + (size_t)(it + 1) * 2048 + dt * 512);
        }

#pragma unroll
        for (int g = 0; g < 4; ++g) {
#pragma unroll
            for (int jt = 0; jt < 2; ++jt) {
                f32x4 z = (f32x4){0.f, 0.f, 0.f, 0.f};
                z = MFMAH(kf[cur][jt][0], qf[g][0], z);
                z = MFMAH(kf[cur][jt][1], qf[g][1], z);
                float e0 = exp2f(z.x), e1 = exp2f(z.y);
                float e2 = exp2f(z.z), e3 = exp2f(z.w);
                lsum[g] += (e0 + e1) + (e2 + e3);
                uint2 pk = make_uint2(pkrtz(e0, e1), pkrtz(e2, e3));
                *(uint2*)(Ps + (g * 16 + q15) * 40 + jt * 16 + quad * 4) = pk;
            }
        }

        f16x8 pf[4];
#pragma unroll
        for (int g = 0; g < 4; ++g)
            pf[g] = *(const f16x8*)(Ps + (g * 16 + q15) * 40 + quad * 8);
#pragma unroll
        for (int dt = 0; dt < 4; ++dt)
#pragma unroll
            for (int g = 0; g < 4; ++g)
                oacc[g][dt] = MFMAH(pf[g], vf[cur][dt], oacc[g][dt]);
    }

#pragma unroll
    for (int g = 0; g < 4; ++g) {
        lsum[g] += __shfl_xor(lsum[g], 16);
        lsum[g] += __shfl_xor(lsum[g], 32);
    }
    if (quad == 0) {
#pragma unroll
        for (int g = 0; g < 4; ++g)
            aF[16384 + w * 64 + g * 16 + q15] = lsum[g];
    }
    __syncthreads();

#define OWRITE(idx)                                                          \
    {                                                                        \
        float* b = aF + (idx) * 4096;                                        \
        _Pragma("unroll") for (int g = 0; g < 4; ++g)                        \
        _Pragma("unroll") for (int dt = 0; dt < 4; ++dt) {                   \
            b[(g * 16 + quad * 4 + 0) * 64 + dt * 16 + q15] = oacc[g][dt].x; \
            b[(g * 16 + quad * 4 + 1) * 64 + dt * 16 + q15] = oacc[g][dt].y; \
            b[(g * 16 + quad * 4 + 2) * 64 + dt * 16 + q15] = oacc[g][dt].z; \
            b[(g * 16 + quad * 4 + 3) * 64 + dt * 16 + q15] = oacc[g][dt].w; \
        }                                                                    \
    }
#define OADD(idx)                                                            \
    {                                                                        \
        const float* b = aF + (idx) * 4096;                                  \
        _Pragma("unroll") for (int g = 0; g < 4; ++g)                        \
        _Pragma("unroll") for (int dt = 0; dt < 4; ++dt) {                   \
            oacc[g][dt].x += b[(g * 16 + quad * 4 + 0) * 64 + dt * 16 + q15];\
            oacc[g][dt].y += b[(g * 16 + quad * 4 + 1) * 64 + dt * 16 + q15];\
            oacc[g][dt].z += b[(g * 16 + quad * 4 + 2) * 64 + dt * 16 + q15];\
            oacc[g][dt].w += b[(g * 16 + quad * 4 + 3) * 64 + dt * 16 + q15];\
        }                                                                    \
    }
    if (w >= 4) OWRITE(w - 4);
    __syncthreads();
    if (w < 4) OADD(w);
    __syncthreads();
    if (w == 2 || w == 3) OWRITE(w - 2);
    __syncthreads();
    if (w < 2) OADD(w);
    __syncthreads();
    if (w < 2) OWRITE(w);
    __syncthreads();

    {
        const int q  = t >> 3;            // 0..63
        const int d0 = (t & 7) * 8;
        float l = 0.f;
#pragma unroll
        for (int i = 0; i < 8; ++i) l += aF[16384 + i * 64 + q];
        const float linv = 1.0f / l;
#pragma unroll
        for (int k2 = 0; k2 < 2; ++k2) {
            float4 a = *(const float4*)&aF[q * 64 + d0 + k2 * 4];
            float4 b = *(const float4*)&aF[4096 + q * 64 + d0 + k2 * 4];
            float4 s;
            s.x = (a.x + b.x) * linv; s.y = (a.y + b.y) * linv;
            s.z = (a.z + b.z) * linv; s.w = (a.w + b.w) * linv;
            *(float4*)(out + (base + q0 + q) * 64 + d0 + k2 * 4) = s;
        }
    }
}

// ---------------------------------------------------------------------------
extern "C" void kernel_launch(void* const* d_in, const int* in_sizes, int n_in,
                              void* d_out, int out_size, void* d_ws, size_t ws_size,
                              hipStream_t stream)
{
    const float* ix = (const float*)d_in[0];
    const float* Wk = (const float*)d_in[1];
    const float* Wq = (const float*)d_in[2];
    const float* Wv = (const float*)d_in[3];
    float* out = (float*)d_out;

    // ws: Qw | Kt | Vt (NROW*64 ushorts each) + WTt (24*192*32 ushorts)
    ushort* Qw  = (ushort*)d_ws;
    ushort* Kt  = Qw + (size_t)NROW * Hm;
    ushort* Vt  = Kt + (size_t)NROW * Hm;
    ushort* WTt = Vt + (size_t)NROW * Hm;

    wconv<<<192, 256, 0, stream>>>(Wq, Wk, Wv, WTt);
    proj<<<512, 256, 0, stream>>>(ix, WTt, Qw, Kt, Vt);
    attn<<<256, 512, 0, stream>>>(Qw, Kt, Vt, out);
}

// Round 9
// 135.493 us; speedup vs baseline: 1.8608x; 1.0031x over previous
//
#include <hip/hip_runtime.h>
#include <math.h>

#define Dm   768
#define Hm   64
#define SEQ  4096
#define NB   4
#define NROW (NB * SEQ)

// scale 1/sqrt(64) and log2(e) folded into Wq at wconv time -> exp2 domain
#define QSCALE (0.125f * 1.4426950408889634f)

typedef _Float16 f16;
typedef __attribute__((ext_vector_type(8))) _Float16 f16x8;
typedef __attribute__((ext_vector_type(2))) __fp16 fp16x2_raw;
typedef __attribute__((ext_vector_type(4))) float f32x4;
typedef unsigned int uint;
typedef unsigned short ushort;

#define MFMAH(A, B, C) __builtin_amdgcn_mfma_f32_16x16x32_f16(A, B, C, 0, 0, 0)

__device__ __forceinline__ uint pkrtz(float a, float b) {
    fp16x2_raw r = __builtin_amdgcn_cvt_pkrtz(a, b);
    return __builtin_bit_cast(uint, r);
}
__device__ __forceinline__ ushort f2h(float f) {
    f16 h = (f16)f;
    return __builtin_bit_cast(ushort, h);
}
union F16x8U { uint u[4]; f16x8 v; };

// ---------------------------------------------------------------------------
// Kernel 0: W -> WTt f16, tiled [kt(24)][c(192)][kk(32)] so proj B-fragment
// loads are coalesced 1KB/instr. c: 0-63 Q (QSCALE folded), 64-127 K,
// 128-191 V.
// ---------------------------------------------------------------------------
__global__ __launch_bounds__(256) void wconv(
    const float* __restrict__ Wq, const float* __restrict__ Wk,
    const float* __restrict__ Wv, ushort* __restrict__ WTt)
{
    const int c   = blockIdx.x;
    const int mat = c >> 6, col = c & 63;
    const float* W = (mat == 0) ? Wq : (mat == 1 ? Wk : Wv);
    const float sc = (mat == 0) ? QSCALE : 1.0f;
    for (int k = threadIdx.x; k < Dm; k += 256)
        WTt[((size_t)(k >> 5) * 192 + c) * 32 + (k & 31)] = f2h(W[k * 64 + col] * sc);
}

// ---------------------------------------------------------------------------
// Kernel 1: f16 MFMA QKV projection, split-K=4. grid 1024 x 256 (12 waves/CU
// via LB(256,3) -- VGPR cap ~170, NO spill risk; R6/R7 spill = 301MB phantom
// writes). Block = 16 rows; wave kh=0..3 owns k in [kh*192, +192) = 6 iters.
// B: SINGLE-buffered 12 frags/iter from L2-hot WTt (one live set).
// A: ix fp32 -> registers, distance-2 ring-3 prefetch (HBM ~900cyc cover).
// 4-way tree combine through LDS (24KB). Epilogue stores all >=32B runs.
// ---------------------------------------------------------------------------
__global__ __launch_bounds__(256, 3) void proj(
    const float* __restrict__ ix, const ushort* __restrict__ WTt,
    ushort* __restrict__ Qw, ushort* __restrict__ Kt, ushort* __restrict__ Vt)
{
    __shared__ __align__(16) float comb[2][3072];   // 24 KiB

    const int t    = threadIdx.x;
    const int lane = t & 63;
    const int kh   = __builtin_amdgcn_readfirstlane(t >> 6);  // split-K index
    const int q15  = lane & 15, quad = lane >> 4;
    const int gr0  = blockIdx.x * 16;

    const float*  Ab = ix + (size_t)(gr0 + q15) * Dm + kh * 192 + quad * 8;
    const ushort* Bb = WTt + ((size_t)(kh * 6) * 192 + q15) * 32 + quad * 8;

    f32x4 acc[12];
#pragma unroll
    for (int ct = 0; ct < 12; ++ct) acc[ct] = (f32x4){0.f, 0.f, 0.f, 0.f};

    f32x4 Af[3][2];   // ring-3, distance-2
#pragma unroll
    for (int i = 0; i < 2; ++i) {
        Af[i][0] = *(const f32x4*)(Ab + i * 32);
        Af[i][1] = *(const f32x4*)(Ab + i * 32 + 4);
    }

#pragma unroll
    for (int it = 0; it < 6; ++it) {
        // B loads first (L2-hot, single buffer, one live set)
        f16x8 Bf[12];
#pragma unroll
        for (int ct = 0; ct < 12; ++ct)
            Bf[ct] = *(const f16x8*)(Bb + (size_t)it * 6144 + ct * 512);

        if (it + 2 < 6) {
            Af[(it + 2) % 3][0] = *(const f32x4*)(Ab + (it + 2) * 32);
            Af[(it + 2) % 3][1] = *(const f32x4*)(Ab + (it + 2) * 32 + 4);
        }

        F16x8U af;
        af.u[0] = pkrtz(Af[it % 3][0].x, Af[it % 3][0].y);
        af.u[1] = pkrtz(Af[it % 3][0].z, Af[it % 3][0].w);
        af.u[2] = pkrtz(Af[it % 3][1].x, Af[it % 3][1].y);
        af.u[3] = pkrtz(Af[it % 3][1].z, Af[it % 3][1].w);
#pragma unroll
        for (int ct = 0; ct < 12; ++ct)
            acc[ct] = MFMAH(af.v, Bf[ct], acc[ct]);
    }

    // ---- 4-way split-K combine: (0+=2, 1+=3), 1 writes, 0 += ----
    if (kh >= 2) {
#pragma unroll
        for (int ct = 0; ct < 12; ++ct)
            *(f32x4*)&comb[kh - 2][(ct * 64 + lane) * 4] = acc[ct];
    }
    __syncthreads();
    if (kh < 2) {
#pragma unroll
        for (int ct = 0; ct < 12; ++ct) {
            f32x4 o = *(const f32x4*)&comb[kh][(ct * 64 + lane) * 4];
            acc[ct].x += o.x; acc[ct].y += o.y; acc[ct].z += o.z; acc[ct].w += o.w;
        }
    }
    __syncthreads();
    if (kh == 1) {
#pragma unroll
        for (int ct = 0; ct < 12; ++ct)
            *(f32x4*)&comb[0][(ct * 64 + lane) * 4] = acc[ct];
    }
    __syncthreads();
    if (kh == 0) {
#pragma unroll
        for (int ct = 0; ct < 12; ++ct) {
            f32x4 o = *(const f32x4*)&comb[0][(ct * 64 + lane) * 4];
            acc[ct].x += o.x; acc[ct].y += o.y; acc[ct].z += o.z; acc[ct].w += o.w;
        }
        const int h16 = (gr0 >> 4) & 1;
        const int n4  = gr0 >> 4;
        const int j32 = gr0 >> 5;
#pragma unroll
        for (int ct = 0; ct < 12; ++ct) {
            float vals[4] = {acc[ct].x, acc[ct].y, acc[ct].z, acc[ct].w};
            if (ct < 4) {                       // Q: row-major, 32B runs
#pragma unroll
                for (int r = 0; r < 4; ++r)
                    Qw[(size_t)(gr0 + quad * 4 + r) * 64 + ct * 16 + q15] = f2h(vals[r]);
            } else if (ct < 8) {                // K tiled: [j>>4][k>>4][j&15][k&15]
#pragma unroll
                for (int r = 0; r < 4; ++r)
                    Kt[(size_t)n4 * 1024 + (ct - 4) * 256 + (quad * 4 + r) * 16 + q15] = f2h(vals[r]);
            } else {                            // V tiled, ushort4 (8B) stores
                ushort4 vv;
                vv.x = f2h(vals[0]); vv.y = f2h(vals[1]);
                vv.z = f2h(vals[2]); vv.w = f2h(vals[3]);
                *(ushort4*)(Vt + (size_t)j32 * 2048 + (ct - 8) * 512 +
                            (h16 * 2 + (quad >> 1)) * 128 + q15 * 8 + (quad & 1) * 4) = vv;
            }
        }
    }
}

// ---------------------------------------------------------------------------
// Kernel 2: f16 MFMA flash attention, software-pipelined. grid 256 x 512.
// Block = 64 queries; wave w owns j in [w*512, +512) = 16 iters of 32 keys.
// K/V fragments: distance-2 ring-3 register prefetch from global (1KB
// contiguous per instr). PV lags QK by ONE iteration with double-buffered
// P strips -> the LDS P round-trip gets a full iteration of latency cover.
// Loop fully unrolled (ring indices constant). No-max exp2 softmax.
// ---------------------------------------------------------------------------
__global__ __launch_bounds__(512, 2) void attn(
    const ushort* __restrict__ Qw, const ushort* __restrict__ Kt,
    const ushort* __restrict__ Vt, float* __restrict__ out)
{
    // floats [0,16384): combine bufs (4 x 4096), aliased by P strips during
    // the loop (shorts [0, 8*5120)). floats [20480,20992): l per wave.
    __shared__ __align__(16) float aF[20992];   // 83968 B
    short* aS = (short*)aF;

    const int t    = threadIdx.x;
    const int lane = t & 63;
    const int w    = __builtin_amdgcn_readfirstlane(t >> 6);
    const int q15  = lane & 15, quad = lane >> 4;

    const int bb    = blockIdx.x;
    const int xcd   = bb & 7;
    const int batch = xcd >> 1;
    const int slot  = (bb >> 3) | ((xcd & 1) << 5);   // 0..63
    const int q0    = slot * 64;
    const size_t base = (size_t)batch * SEQ;

    f16x8 qf[4][2];
#pragma unroll
    for (int g = 0; g < 4; ++g)
#pragma unroll
        for (int h = 0; h < 2; ++h)
            qf[g][h] = *(const f16x8*)(Qw + (base + q0 + g * 16 + q15) * 64 + h * 32 + quad * 8);

    f32x4 oacc[4][4];
#pragma unroll
    for (int g = 0; g < 4; ++g)
#pragma unroll
        for (int dt = 0; dt < 4; ++dt) oacc[g][dt] = (f32x4){0.f, 0.f, 0.f, 0.f};
    float lsum[4] = {0.f, 0.f, 0.f, 0.f};

    const size_t j0g = base + w * 512;
    const ushort* Kfb = Kt + (j0g >> 4) * 1024;
    const ushort* Vfb = Vt + (j0g >> 5) * 2048 + lane * 8;
    short* Ps = aS + w * 5120;                          // 2 bufs x [64 q][40]

    int koff[2][2];
#pragma unroll
    for (int jt = 0; jt < 2; ++jt)
#pragma unroll
        for (int h = 0; h < 2; ++h)
            koff[jt][h] = jt * 1024 + h * 512 + (quad >> 1) * 256 + q15 * 16 + (quad & 1) * 8;

    f16x8 kf[3][2][2], vf[3][4];   // ring-3

#define LOADKV(slotc, i)                                                       \
    {                                                                          \
        _Pragma("unroll") for (int jt = 0; jt < 2; ++jt)                       \
        _Pragma("unroll") for (int h = 0; h < 2; ++h)                          \
            kf[slotc][jt][h] = *(const f16x8*)(Kfb + (size_t)(i) * 2048 + koff[jt][h]); \
        _Pragma("unroll") for (int dt = 0; dt < 4; ++dt)                       \
            vf[slotc][dt] = *(const f16x8*)(Vfb + (size_t)(i) * 2048 + dt * 512); \
    }
#define QKSTEP(slotc, pb)                                                      \
    {                                                                          \
        _Pragma("unroll") for (int g = 0; g < 4; ++g)                          \
        _Pragma("unroll") for (int jt = 0; jt < 2; ++jt) {                     \
            f32x4 z = (f32x4){0.f, 0.f, 0.f, 0.f};                             \
            z = MFMAH(kf[slotc][jt][0], qf[g][0], z);                          \
            z = MFMAH(kf[slotc][jt][1], qf[g][1], z);                          \
            float e0 = exp2f(z.x), e1 = exp2f(z.y);                            \
            float e2 = exp2f(z.z), e3 = exp2f(z.w);                            \
            lsum[g] += (e0 + e1) + (e2 + e3);                                  \
            uint2 pk = make_uint2(pkrtz(e0, e1), pkrtz(e2, e3));               \
            *(uint2*)(Ps + (pb) * 2560 + (g * 16 + q15) * 40 + jt * 16 + quad * 4) = pk; \
        }                                                                      \
    }
#define PVSTEP(slotc, pb)                                                      \
    {                                                                          \
        f16x8 pf[4];                                                           \
        _Pragma("unroll") for (int g = 0; g < 4; ++g)                          \
            pf[g] = *(const f16x8*)(Ps + (pb) * 2560 + (g * 16 + q15) * 40 + quad * 8); \
        _Pragma("unroll") for (int dt = 0; dt < 4; ++dt)                       \
        _Pragma("unroll") for (int g = 0; g < 4; ++g)                          \
            oacc[g][dt] = MFMAH(pf[g], vf[slotc][dt], oacc[g][dt]);            \
    }

    LOADKV(0, 0);
    LOADKV(1, 1);
    QKSTEP(0, 0);
#pragma unroll
    for (int i = 0; i < 16; ++i) {
        if (i + 2 < 16) LOADKV((i + 2) % 3, i + 2);
        if (i + 1 < 16) QKSTEP((i + 1) % 3, (i + 1) & 1);
        PVSTEP(i % 3, i & 1);
    }

    // ---- l: quad-reduce, publish per wave ----
#pragma unroll
    for (int g = 0; g < 4; ++g) {
        lsum[g] += __shfl_xor(lsum[g], 16);
        lsum[g] += __shfl_xor(lsum[g], 32);
    }
    if (quad == 0) {
#pragma unroll
        for (int g = 0; g < 4; ++g)
            aF[20480 + w * 64 + g * 16 + q15] = lsum[g];
    }
    __syncthreads();   // P strips dead; l published; combine bufs usable

    // ---- 8-way tree combine of o through LDS ----
#define OWRITE(idx)                                                          \
    {                                                                        \
        float* b = aF + (idx) * 4096;                                        \
        _Pragma("unroll") for (int g = 0; g < 4; ++g)                        \
        _Pragma("unroll") for (int dt = 0; dt < 4; ++dt) {                   \
            b[(g * 16 + quad * 4 + 0) * 64 + dt * 16 + q15] = oacc[g][dt].x; \
            b[(g * 16 + quad * 4 + 1) * 64 + dt * 16 + q15] = oacc[g][dt].y; \
            b[(g * 16 + quad * 4 + 2) * 64 + dt * 16 + q15] = oacc[g][dt].z; \
            b[(g * 16 + quad * 4 + 3) * 64 + dt * 16 + q15] = oacc[g][dt].w; \
        }                                                                    \
    }
#define OADD(idx)                                                            \
    {                                                                        \
        const float* b = aF + (idx) * 4096;                                  \
        _Pragma("unroll") for (int g = 0; g < 4; ++g)                        \
        _Pragma("unroll") for (int dt = 0; dt < 4; ++dt) {                   \
            oacc[g][dt].x += b[(g * 16 + quad * 4 + 0) * 64 + dt * 16 + q15];\
            oacc[g][dt].y += b[(g * 16 + quad * 4 + 1) * 64 + dt * 16 + q15];\
            oacc[g][dt].z += b[(g * 16 + quad * 4 + 2) * 64 + dt * 16 + q15];\
            oacc[g][dt].w += b[(g * 16 + quad * 4 + 3) * 64 + dt * 16 + q15];\
        }                                                                    \
    }
    if (w >= 4) OWRITE(w - 4);
    __syncthreads();
    if (w < 4) OADD(w);
    __syncthreads();
    if (w == 2 || w == 3) OWRITE(w - 2);
    __syncthreads();
    if (w < 2) OADD(w);
    __syncthreads();
    if (w < 2) OWRITE(w);
    __syncthreads();

    {
        const int q  = t >> 3;            // 0..63
        const int d0 = (t & 7) * 8;
        float l = 0.f;
#pragma unroll
        for (int i = 0; i < 8; ++i) l += aF[20480 + i * 64 + q];
        const float linv = 1.0f / l;
#pragma unroll
        for (int k2 = 0; k2 < 2; ++k2) {
            float4 a = *(const float4*)&aF[q * 64 + d0 + k2 * 4];
            float4 b = *(const float4*)&aF[4096 + q * 64 + d0 + k2 * 4];
            float4 s;
            s.x = (a.x + b.x) * linv; s.y = (a.y + b.y) * linv;
            s.z = (a.z + b.z) * linv; s.w = (a.w + b.w) * linv;
            *(float4*)(out + (base + q0 + q) * 64 + d0 + k2 * 4) = s;
        }
    }
}

// ---------------------------------------------------------------------------
extern "C" void kernel_launch(void* const* d_in, const int* in_sizes, int n_in,
                              void* d_out, int out_size, void* d_ws, size_t ws_size,
                              hipStream_t stream)
{
    const float* ix = (const float*)d_in[0];
    const float* Wk = (const float*)d_in[1];
    const float* Wq = (const float*)d_in[2];
    const float* Wv = (const float*)d_in[3];
    float* out = (float*)d_out;

    // ws: Qw | Kt | Vt (NROW*64 ushorts each) + WTt (24*192*32 ushorts)
    ushort* Qw  = (ushort*)d_ws;
    ushort* Kt  = Qw + (size_t)NROW * Hm;
    ushort* Vt  = Kt + (size_t)NROW * Hm;
    ushort* WTt = Vt + (size_t)NROW * Hm;

    wconv<<<192, 256, 0, stream>>>(Wq, Wk, Wv, WTt);
    proj<<<1024, 256, 0, stream>>>(ix, WTt, Qw, Kt, Vt);
    attn<<<256, 512, 0, stream>>>(Qw, Kt, Vt, out);
}